// Round 3
// baseline (1186.748 us; speedup 1.0000x reference)
//
#include <hip/hip_runtime.h>
#include <stdint.h>

typedef __attribute__((ext_vector_type(8))) short short8;
typedef __attribute__((ext_vector_type(4))) float floatx4;
typedef __attribute__((ext_vector_type(4))) unsigned uintx4;

#define MFMA16(a, b, c) __builtin_amdgcn_mfma_f32_16x16x32_bf16(a, b, c, 0, 0, 0)

// Pack two fp32 -> bf16 pair (lo, hi): +0x8000 round-half-up + one v_perm.
__device__ __forceinline__ unsigned pkbf(float lo, float hi) {
    const unsigned a = __builtin_bit_cast(unsigned, lo) + 0x8000u;
    const unsigned b = __builtin_bit_cast(unsigned, hi) + 0x8000u;
    return __builtin_amdgcn_perm(b, a, 0x07060302u);  // {b.hi16, a.hi16}
}

// == R16: BARRIER-FREE transposed pipeline ==
// R14/R15 post-mortem: hot live set is ~110-125 regs (VGPR counter reports
// half: 64/32/48 <-> budgets 128/64/96); N-split needs the 128 budget = 4
// waves/EU, and wave-scaling was saturating (287/220/205). The real loss at
// R13 was barrier lockstep: MfmaUtil 20 / VALU 42, floors VALU 82us,
// MFMA 46us, LDS 25us vs 196us actual -> ~110us of barrier serialization
// from the h1/h2 cross-wave exchange (3 syncthreads / 64 rows).
// This kernel transposes the MLP: h^T = W^T x feats^T, MFMA-M = hidden,
// MFMA-N = batch rows. Each wave owns 16 rows END-TO-END:
//  * C-layout -> next-layer B-frag conversion is IN-REGISTER:
//    hid = kt*32+q*8+j lives at source lane (c, 2(q&1)+(j>>2)), mtile
//    2kt+(q>>1), rr=j&3 -> 8 ds_bpermute + 4 cndmask per k-tile
//    (addrA = c+32(q&1), addrB = addrA+16 lanes; X/Y select by q>>1).
//  * W2^T staged per dir as a 32KB A-frag image; frags streamed per use
//    (32 ds_read_b128 / wave-tile; LDS pipe ~35us << VALU floor).
//  * W1^T/b1/b2/W3 images: 2KB/512B/512B/512B. b-images read as MFMA
//    C-init (broadcast b128, free). No h1/h2 LDS buffers at all.
//  * ZERO __syncthreads in the row loop; ~3/dir around weight staging.
//  * Live set ~70-80 regs; LDS 38912 B -> 4 WGs/CU (occupancy no longer
//    gates: waves progress independently).
__global__ __launch_bounds__(256)
__attribute__((amdgpu_waves_per_eu(4, 8)))
void NeuralNet_37615323578557_kernel(
        const float* __restrict__ x, const float* __restrict__ t,
        const float* __restrict__ fW1, const float* __restrict__ fb1,
        const float* __restrict__ fW2, const float* __restrict__ fb2,
        const float* __restrict__ fW3, const float* __restrict__ fb3,
        const float* __restrict__ gW1, const float* __restrict__ gb1,
        const float* __restrict__ gW2, const float* __restrict__ gb2,
        const float* __restrict__ gW3, const float* __restrict__ gb3,
        const float* __restrict__ iW1, const float* __restrict__ ib1,
        const float* __restrict__ iW2, const float* __restrict__ ib2,
        const float* __restrict__ iW3, const float* __restrict__ ib3,
        float* __restrict__ out) {
    __shared__ unsigned       w2img[8192];   // 32 KB W2^T A-frag image
    __shared__ unsigned       w1img[512];    // 2 KB: [128 hid][4 u32] (k 0..7)
    __shared__ float          b1img[128];    // 512 B
    __shared__ float          b2img[128];    // 512 B
    __shared__ unsigned short w3img[256];    // 512 B W3^T frag image
    __shared__ float          accT[512];     // 2 KB output accumulator
    __shared__ float          initbuf[128];  // 512 B init-MLP scratch

    const int tid  = threadIdx.x;
    const int lane = tid & 63;
    const int w    = tid >> 6;      // wave 0..3
    const int c    = lane & 15;
    const int q    = lane >> 4;
    const int b0   = blockIdx.x;    // one batch per WG

    // bpermute byte-addresses for the C-layout -> B-frag lane exchange
    const int pA = (c + ((q & 1) << 5)) << 2;
    const int pB = pA + 64;

    accT[tid] = 0.0f;
    accT[tid + 256] = 0.0f;

    const float* xb = x + (size_t)b0 * 514;
    const float  tv = t[b0];
    const float2 pt = *(const float2*)(xb + 512);   // x[b, T, :]
    const unsigned ptp = pkbf(pt.x, pt.y);

// C-layout c1[8] (f32) -> B-frags bf[4]: relu + pack + lane-exchange.
#define CONV4(CARR, BOUT)                                                     \
    _Pragma("unroll")                                                         \
    for (int kt = 0; kt < 4; ++kt) {                                          \
        const floatx4 xa = CARR[2 * kt], ya = CARR[2 * kt + 1];               \
        const unsigned X0 = pkbf(fmaxf(xa[0], 0.f), fmaxf(xa[1], 0.f));       \
        const unsigned X1 = pkbf(fmaxf(xa[2], 0.f), fmaxf(xa[3], 0.f));       \
        const unsigned Y0 = pkbf(fmaxf(ya[0], 0.f), fmaxf(ya[1], 0.f));       \
        const unsigned Y1 = pkbf(fmaxf(ya[2], 0.f), fmaxf(ya[3], 0.f));       \
        const int x0a = __builtin_amdgcn_ds_bpermute(pA, (int)X0);            \
        const int y0a = __builtin_amdgcn_ds_bpermute(pA, (int)Y0);            \
        const int x1a = __builtin_amdgcn_ds_bpermute(pA, (int)X1);            \
        const int y1a = __builtin_amdgcn_ds_bpermute(pA, (int)Y1);            \
        const int x0b = __builtin_amdgcn_ds_bpermute(pB, (int)X0);            \
        const int y0b = __builtin_amdgcn_ds_bpermute(pB, (int)Y0);            \
        const int x1b = __builtin_amdgcn_ds_bpermute(pB, (int)X1);            \
        const int y1b = __builtin_amdgcn_ds_bpermute(pB, (int)Y1);            \
        const bool lo = (q < 2);                                              \
        uintx4 uv;                                                            \
        uv.x = (unsigned)(lo ? x0a : y0a);                                    \
        uv.y = (unsigned)(lo ? x1a : y1a);                                    \
        uv.z = (unsigned)(lo ? x0b : y0b);                                    \
        uv.w = (unsigned)(lo ? x1b : y1b);                                    \
        BOUT[kt] = __builtin_bit_cast(short8, uv);                            \
    }

    #pragma unroll 1
    for (int dir = 0; dir < 2; ++dir) {
        const float* W1 = dir ? gW1 : fW1;
        const float* B1 = dir ? gb1 : fb1;
        const float* W2 = dir ? gW2 : fW2;
        const float* B2 = dir ? gb2 : fb2;
        const float* W3 = dir ? gW3 : fW3;
        const float* B3 = dir ? gb3 : fb3;
        const int posoff = (1 - dir) * 2;

        __syncthreads();  // prev-dir image reads done; accT zero ordered

        // ---- stage W2^T A-frag image (32 KB) ----
        // Element (m,k): u32 addr = ((m>>4)*4 + (k>>5))*256
        //                         + (((k>>3)&3)*16 + (m&15))*4 + ((k&7)>>1).
        // Thread: k rows {2*lane, 2*lane+1}; wave w covers m in
        // [16w,16w+16) per half (half*64 offset). rot spreads write banks
        // (<=4-way, cold path). unroll 4 caps in-flight loads.
        {
            const int k0  = lane << 1;
            const int ks  = k0 >> 5;
            const int q2  = (k0 >> 3) & 3;
            const int j0h = (k0 & 7) >> 1;
            const int rot = (tid >> 2) & 7;
            #pragma unroll
            for (int half = 0; half < 2; ++half) {
                const int mb = (half << 6) + (w << 4);
                const float* r0p = W2 + k0 * 128 + mb;
                const float* r1p = r0p + 128;
                #pragma unroll 4
                for (int nn2 = 0; nn2 < 8; ++nn2) {
                    const int off = ((nn2 + rot) & 7) << 1;
                    const float2 v0 = *(const float2*)(r0p + off);
                    const float2 v1 = *(const float2*)(r1p + off);
                    #pragma unroll
                    for (int e = 0; e < 2; ++e) {
                        const int m = mb + off + e;
                        const unsigned pv = pkbf(e ? v0.y : v0.x, e ? v1.y : v1.x);
                        const int ua = (((m >> 4) << 2) + ks) * 256
                                     + ((q2 << 4) + (m & 15)) * 4 + j0h;
                        w2img[ua] = pv;
                    }
                }
            }
        }
        // ---- stage W1^T image: [128 hid][4 u32] (k pairs 0..7) ----
        #pragma unroll
        for (int rep = 0; rep < 2; ++rep) {
            const int v   = tid + (rep << 8);
            const int hid = v >> 2, up = v & 3;
            w1img[v] = pkbf(W1[(2 * up) * 128 + hid], W1[(2 * up + 1) * 128 + hid]);
        }
        // ---- biases ----
        if (tid < 128) b1img[tid] = B1[tid];
        else           b2img[tid - 128] = B2[tid - 128];
        // ---- W3^T frag image (verbatim-proven layout) ----
        if (tid < 128) {
            const int ks3 = tid >> 5, q3 = (tid >> 3) & 3;
            const int c3 = (tid >> 2) & 1, jp = tid & 3;
            const int k = ks3 * 32 + q3 * 8 + jp * 2;
            ((unsigned*)w3img)[tid] = pkbf(W3[k * 2 + c3], W3[(k + 1) * 2 + c3]);
        }
        const float b3v0 = B3[0], b3v1 = B3[1];
        __syncthreads();  // images ready

        // ---- init MLP: wave 0, once; others proceed (no barrier after).
        // Writes accT[0..1] (dir-0 adds only touch idx>=2; dir-1 adds are
        // ordered behind the dir-1 staging barrier). atomicAdd for safety.
        if (dir == 0 && w == 0) {
            const float f0 = xb[0], f1 = xb[1];
            const int u0 = lane, u1 = lane + 64;
            const float h0 = fmaxf(iW1[u0] * f0 + iW1[128 + u0] * f1 + iW1[256 + u0] * tv + ib1[u0], 0.f);
            const float h1 = fmaxf(iW1[u1] * f0 + iW1[128 + u1] * f1 + iW1[256 + u1] * tv + ib1[u1], 0.f);
            initbuf[u0] = h0;
            initbuf[u1] = h1;
            float a0 = ib2[lane], a1 = ib2[lane + 64];
            for (int k = 0; k < 128; ++k) {
                const float hv = initbuf[k];
                a0 += hv * iW2[k * 128 + lane];
                a1 += hv * iW2[k * 128 + lane + 64];
            }
            a0 = fmaxf(a0, 0.f); a1 = fmaxf(a1, 0.f);
            float p0 = a0 * iW3[lane * 2 + 0] + a1 * iW3[(lane + 64) * 2 + 0];
            float p1 = a0 * iW3[lane * 2 + 1] + a1 * iW3[(lane + 64) * 2 + 1];
            #pragma unroll
            for (int m = 1; m < 64; m <<= 1) {
                p0 += __shfl_xor(p0, m, 64);
                p1 += __shfl_xor(p1, m, 64);
            }
            if (lane == 0) {
                atomicAdd(&accT[0], p0 + ib3[0]);
                atomicAdd(&accT[1], p1 + ib3[1]);
            }
        }

        // ================= barrier-free row loop =================
        #pragma unroll 1
        for (int it = 0; it < 4; ++it) {
            const int r = it * 64 + (w << 4) + c;   // this lane's batch row

            // ---- feats B-frag (real only in q==0 lanes) ----
            short8 af;
            {
                uintx4 fv = {0u, 0u, 0u, 0u};
                if (q == 0 && r < 255) {
                    const float2 xi  = *(const float2*)(xb + 2 * r);
                    const float2 xi1 = *(const float2*)(xb + 2 * r + 2);
                    const float nv = (float)(dir ? r : (r + 1)) * (1.0f / 256.0f);
                    if (dir == 0) {  // [x_{i+1}, t, x_i, (i+1)/T, pt]
                        fv.x = pkbf(xi1.x, xi1.y);
                        fv.y = pkbf(tv, xi.x);
                        fv.z = pkbf(xi.y, nv);
                    } else {         // [x_i, t, x_{i+1}, i/T, pt]
                        fv.x = pkbf(xi.x, xi.y);
                        fv.y = pkbf(tv, xi1.x);
                        fv.z = pkbf(xi1.y, nv);
                    }
                    fv.w = ptp;
                }
                af = __builtin_bit_cast(short8, fv);
            }

            // ---- layer 1: c1[mt] = W1^T x feats^T + b1 (C: hid x rows) ----
            floatx4 c1[8];
            #pragma unroll
            for (int mt = 0; mt < 8; ++mt)
                c1[mt] = *(const floatx4*)&b1img[(mt << 4) + (q << 2)];
            #pragma unroll
            for (int mt = 0; mt < 8; ++mt) {
                short8 a1 = {0, 0, 0, 0, 0, 0, 0, 0};
                if (q == 0)
                    a1 = *(const short8*)&w1img[((mt << 4) + c) << 2];
                c1[mt] = MFMA16(a1, af, c1[mt]);
            }

            // ---- convert h1 C-layout -> B-frags (relu inside) ----
            short8 bf[4];
            CONV4(c1, bf)

            // ---- layer 2: c2[mt] += A2(mt,kt) x bf[kt], bias-init ----
            floatx4 c2[8];
            #pragma unroll
            for (int mt = 0; mt < 8; ++mt)
                c2[mt] = *(const floatx4*)&b2img[(mt << 4) + (q << 2)];
            {
                const unsigned short* w2s = (const unsigned short*)w2img;
                #pragma unroll
                for (int kt = 0; kt < 4; ++kt)
                    #pragma unroll
                    for (int mt = 0; mt < 8; ++mt) {
                        const short8 a2 = *(const short8*)
                            &w2s[(((mt << 2) + kt) << 9) + (lane << 3)];
                        c2[mt] = MFMA16(a2, bf[kt], c2[mt]);
                    }
            }

            // ---- convert h2 -> B-frags (layer-2 relu inside) ----
            short8 bg[4];
            CONV4(c2, bg)

            // ---- layer 3: out^T = W3^T x h2^T + b3 (rows 0,1 real) ----
            floatx4 c3 = {q == 0 ? b3v0 : 0.f, q == 0 ? b3v1 : 0.f, 0.f, 0.f};
            #pragma unroll
            for (int kt = 0; kt < 4; ++kt) {
                const short8 a3 = *(const short8*)
                    &w3img[(kt << 6) + (q << 4) + ((c & 1) << 3)];
                c3 = MFMA16(a3, bg[kt], c3);
            }
            if (q == 0 && r < 255) {
                // pos = r + 1 - dir -> idx = 2r + posoff + coldim
                atomicAdd(&accT[2 * r + posoff + 0], c3[0]);  // ds_add_f32
                atomicAdd(&accT[2 * r + posoff + 1], c3[1]);
            }
        }
    }

    __syncthreads();  // accT complete
    if (tid < 128)
        ((float4*)(out + (size_t)b0 * 512))[tid] = ((const float4*)accT)[tid];
#undef CONV4
}

extern "C" void kernel_launch(void* const* d_in, const int* in_sizes, int n_in,
                              void* d_out, int out_size, void* d_ws, size_t ws_size,
                              hipStream_t stream) {
    (void)in_sizes; (void)n_in; (void)d_ws; (void)ws_size; (void)out_size;
    const float* x   = (const float*)d_in[0];
    const float* t   = (const float*)d_in[1];
    const float* fW1 = (const float*)d_in[2];
    const float* fb1 = (const float*)d_in[3];
    const float* fW2 = (const float*)d_in[4];
    const float* fb2 = (const float*)d_in[5];
    const float* fW3 = (const float*)d_in[6];
    const float* fb3 = (const float*)d_in[7];
    const float* gW1 = (const float*)d_in[8];
    const float* gb1 = (const float*)d_in[9];
    const float* gW2 = (const float*)d_in[10];
    const float* gb2 = (const float*)d_in[11];
    const float* gW3 = (const float*)d_in[12];
    const float* gb3 = (const float*)d_in[13];
    const float* iW1 = (const float*)d_in[14];
    const float* ib1 = (const float*)d_in[15];
    const float* iW2 = (const float*)d_in[16];
    const float* ib2 = (const float*)d_in[17];
    const float* iW3 = (const float*)d_in[18];
    const float* ib3 = (const float*)d_in[19];
    float* out = (float*)d_out;

    NeuralNet_37615323578557_kernel<<<dim3(4096), 256, 0, stream>>>(
        x, t, fW1, fb1, fW2, fb2, fW3, fb3,
        gW1, gb1, gW2, gb2, gW3, gb3,
        iW1, ib1, iW2, ib2, iW3, ib3, out);
}

// Round 5
// 821.158 us; speedup vs baseline: 1.4452x; 1.4452x over previous
//
#include <hip/hip_runtime.h>
#include <stdint.h>

typedef __attribute__((ext_vector_type(8))) short short8;
typedef __attribute__((ext_vector_type(4))) float floatx4;

#define MFMA16(a, b, c) __builtin_amdgcn_mfma_f32_16x16x32_bf16(a, b, c, 0, 0, 0)

// Pack two fp32 -> bf16 pair (lo, hi) in ONE v_perm_b32 after +0x8000
// round-half-up (vs software RNE: ~10 VALU -> 3 VALU per pair).
__device__ __forceinline__ unsigned pkbf(float lo, float hi) {
    const unsigned a = __builtin_bit_cast(unsigned, lo) + 0x8000u;
    const unsigned b = __builtin_bit_cast(unsigned, hi) + 0x8000u;
    return __builtin_amdgcn_perm(b, a, 0x07060302u);  // {b.hi16, a.hi16}
}
__device__ __forceinline__ unsigned short f2bf(float x) {
    unsigned u = __builtin_bit_cast(unsigned, x);
    u = (u + 0x7fffu + ((u >> 16) & 1u)) >> 16;  // RNE (cold paths only)
    return (unsigned short)u;
}

// Activation tiles are 32x128 bf16 viewed as u32 pairs: u32 index u of a row
// holds bf16 cols (2u, 2u+1). 16B chunks XOR-swizzled by row&15: b32 C-layout
// writes stay <=2-way (free), b128 A-frag reads are bank-balanced.
__device__ __forceinline__ int hphys(int row, int u) {
    return row * 64 + ((((u >> 2) ^ (row & 15)) << 2) | (u & 3));
}

// == R18: R17 pair decomposition, LDS-overflow bug FIXED ==
// R17 failure: 64-row pair tiles need 4096 u32 per h-buffer but only 2048
// were allocated -> pair0 h1/h2 overlapped, pair1 ran past sbuf into
// fbuf/accT/w3img (absmax 42.7). Fix: 32-ROW pair tiles -> each h-buffer is
// exactly 32x64 = 2048 u32; the R17 pointers become correct unchanged.
//  * 16 tiles of 32 rows; pair p = w>>1 owns tt = 2s+p, s in [0,8);
//  * N-split within pair: wave v = w&1 owns cols [64v,64v+64)
//    (w2f = 4ntl x 4kt = 64 VGPRs; staged-block index = 4*ntl+kss);
//  * L1/L2: mt in [0,2); L3: wave v = row-block 16v, full k (4 MFMAs);
//  * feats: 32 rows/s staged by pair's v==0 wave, lanes 0..31;
//  * barrier count per ROW = R13; 2x MFMA per wave per interval;
//    h-read amplification HALVED (2 waves x 8 KB per 32-row tile).
// Regs ~160 live (w2f 64 is the price of 2-way tile sharing) -> (3,4) =
// 168 budget, 12 waves/CU (ragged 768/768/512 dispatch). Gate: FETCH must
// stay ~MB-scale (no spill); if >=196 us clean, pair thesis is dead.
__global__ __launch_bounds__(256)
__attribute__((amdgpu_waves_per_eu(3, 4)))
void NeuralNet_37615323578557_kernel(
        const float* __restrict__ x, const float* __restrict__ t,
        const float* __restrict__ fW1, const float* __restrict__ fb1,
        const float* __restrict__ fW2, const float* __restrict__ fb2,
        const float* __restrict__ fW3, const float* __restrict__ fb3,
        const float* __restrict__ gW1, const float* __restrict__ gb1,
        const float* __restrict__ gW2, const float* __restrict__ gb2,
        const float* __restrict__ gW3, const float* __restrict__ gb3,
        const float* __restrict__ iW1, const float* __restrict__ ib1,
        const float* __restrict__ iW2, const float* __restrict__ ib2,
        const float* __restrict__ iW3, const float* __restrict__ ib3,
        float* __restrict__ out) {
    __shared__ unsigned sbuf[8192];             // 32 KB: W2 image / 2x(h1|h2)
    __shared__ unsigned short fbuf[2 * 256];    // 1 KB: feats per pair / init
    __shared__ float accT[2 * 256 * 2];         // 4 KB output accumulator
    __shared__ unsigned short w3img[256];       // 512 B W3 B-frag image

    const int tid  = threadIdx.x;
    const int lane = tid & 63;
    const int w    = tid >> 6;      // wave 0..3
    const int p    = w >> 1;        // pair 0..1
    const int v    = w & 1;         // wave-in-pair: owns cols [64v, 64v+64)
    const int c    = lane & 15;     // MFMA low index (m for A, n for B/C)
    const int q    = lane >> 4;     // MFMA quad
    const int b0   = blockIdx.x * 2;

    unsigned* const hp1 = sbuf + p * 4096;          // pair h1: 32x64 u32 (8 KB)
    unsigned* const hp2 = sbuf + p * 4096 + 2048;   // pair h2: 32x64 u32 (8 KB)

    // ---- zero the output accumulator ----
    #pragma unroll
    for (int k = 0; k < 4; ++k) accT[tid + k * 256] = 0.0f;
    __syncthreads();

    // ---- init MLP: waves 0,1 handle b_local = w (pure fp32 VALU) ----
    // Scratch = all of fbuf (512 B/wave); done before first dir barrier, so
    // no conflict with feats staging.
    if (w < 2) {
        float* h1s = (float*)fbuf + w * 128;
        const int b = b0 + w;
        const float* xb = x + (size_t)b * 514;
        const float f0 = xb[0], f1 = xb[1], f2 = t[b];
        const int u0 = lane, u1 = lane + 64;
        const float h0 = fmaxf(iW1[u0] * f0 + iW1[128 + u0] * f1 + iW1[256 + u0] * f2 + ib1[u0], 0.f);
        const float h1 = fmaxf(iW1[u1] * f0 + iW1[128 + u1] * f1 + iW1[256 + u1] * f2 + ib1[u1], 0.f);
        h1s[u0] = h0;
        h1s[u1] = h1;
        float a0 = ib2[lane], a1 = ib2[lane + 64];
        for (int k = 0; k < 128; ++k) {
            const float hv = h1s[k];
            a0 += hv * iW2[k * 128 + lane];
            a1 += hv * iW2[k * 128 + lane + 64];
        }
        a0 = fmaxf(a0, 0.f); a1 = fmaxf(a1, 0.f);
        float p0 = a0 * iW3[lane * 2 + 0] + a1 * iW3[(lane + 64) * 2 + 0];
        float p1 = a0 * iW3[lane * 2 + 1] + a1 * iW3[(lane + 64) * 2 + 1];
        #pragma unroll
        for (int m = 1; m < 64; m <<= 1) {
            p0 += __shfl_xor(p0, m, 64);
            p1 += __shfl_xor(p1, m, 64);
        }
        if (lane == 0) {
            accT[w * 512 + 0] += p0 + ib3[0];
            accT[w * 512 + 1] += p1 + ib3[1];
        }
    }

    for (int dir = 0; dir < 2; ++dir) {
        const float* W1 = dir ? gW1 : fW1;
        const float* B1 = dir ? gb1 : fb1;
        const float* W2 = dir ? gW2 : fW2;
        const float* B2 = dir ? gb2 : fb2;
        const float* W3 = dir ? gW3 : fW3;
        const float* B3 = dir ? gb3 : fb3;
        const int posoff = (1 - dir) * 2;

        __syncthreads();  // prev dir's sbuf/w3img reads / init fbuf done

        // ---- stage W2 B-frag image in two 16 KB col-halves (R14-verified) ----
        // Element (k,n) -> block B=((n>>5)*2+(n&1))*4+(k>>5) (-16 for half 1),
        //   ushort idx = B*512 + (((k>>3)&3)*16 + ((n>>1)&15))*8 + (k&7).
        // Thread t: rows {k0,k0+1}, 16 cols with float2-rotation (R6 rot-map,
        // verified 0 write conflicts). unroll 4 caps in-flight payload regs.
        short8 w2f[4][4];
        {
            const int k0  = (tid & 63) << 1;
            const int rot = (tid >> 2) & 7;
            const int ks  = k0 >> 5;
            const int q2  = (k0 >> 3) & 3;
            const int j0  = k0 & 7;         // even
            const int usb = (q2 << 4) * 8 + j0;   // + B*512 + n2*8
            const int cg  = (tid >> 6) << 4;

            #pragma unroll
            for (int half = 0; half < 2; ++half) {
                const int c0 = half * 64 + cg;
                const float* r0p = &W2[k0 * 128 + c0];
                const float* r1p = r0p + 128;
                #pragma unroll 4
                for (int nn2 = 0; nn2 < 8; ++nn2) {
                    const int off = ((nn2 + rot) & 7) << 1;
                    const float2 v0 = *(const float2*)(r0p + off);
                    const float2 v1 = *(const float2*)(r1p + off);
                    #pragma unroll
                    for (int e = 0; e < 2; ++e) {
                        const int n = c0 + off + e;
                        const unsigned pv = pkbf(e ? v0.y : v0.x, e ? v1.y : v1.x);
                        const int B = (((n >> 5) * 2 + (n & 1)) * 4 + ks) - half * 16;
                        const int us = B * 512 + ((n >> 1) & 15) * 8 + usb;
                        sbuf[us >> 1] = pv;
                    }
                }
                // ---- W3 B-frag image (512 B; k-pair per thread), once ----
                if (half == 0 && tid < 128) {
                    const int ks3 = tid >> 5, q3 = (tid >> 3) & 3;
                    const int c3 = (tid >> 2) & 1, jp = tid & 3;
                    const int k = ks3 * 32 + q3 * 8 + jp * 2;
                    ((unsigned*)w3img)[tid] = pkbf(W3[k * 2 + c3], W3[(k + 1) * 2 + c3]);
                }
                __syncthreads();  // half-image complete
                // waves with v==half own these 64 cols: blocks 4*ntl+kss
                if (v == half) {
                    const unsigned short* img = (const unsigned short*)sbuf;
                    #pragma unroll
                    for (int ntl = 0; ntl < 4; ++ntl)
                        #pragma unroll
                        for (int kss = 0; kss < 4; ++kss)
                            w2f[ntl][kss] = *(const short8*)
                                &img[((ntl * 4 + kss) << 9) + lane * 8];
                }
                __syncthreads();  // image consumed; sbuf reusable
            }
        }

        // ---- small weight frags (W1, biases) straight to regs ----
        // col(ntl,c) = 64v + 32*(ntl>>1) + 2c + (ntl&1)
        short8 w1f[4];
        float  b1v[4], b2v[4];
        #pragma unroll
        for (int ntl = 0; ntl < 4; ++ntl) {
            const int col = (v << 6) + ((ntl >> 1) << 5) + 2 * c + (ntl & 1);
            b1v[ntl] = B1[col];
            b2v[ntl] = B2[col];
            short8 f = {0, 0, 0, 0, 0, 0, 0, 0};
            if (q == 0) {  // K padded 8 -> 32: only quad 0 holds real W1 rows
                #pragma unroll
                for (int j = 0; j < 8; ++j) f[j] = (short)f2bf(W1[j * 128 + col]);
            }
            w1f[ntl] = f;
        }
        const float b3c = (c < 2) ? B3[c] : 0.0f;

        // ======== pair-independent tile stream: pair p does tt = 2s+p ========
        #pragma unroll 1
        for (int s = 0; s < 8; ++s) {
            const int tt = (s << 1) | p;
            const int r0 = tt * 32;

            // ---- stage features: pair's lead wave, lanes 0..31 (32 rows) ----
            if (v == 0 && lane < 32) {
                const int r = r0 + lane;
                unsigned f0 = 0, f1 = 0, f2 = 0, f3 = 0;
                if (r < 510) {
                    const int bl = (r >= 255) ? 1 : 0;
                    const int i  = r - bl * 255;
                    const float* xb = x + (size_t)(b0 + bl) * 514;
                    const float2 xi  = *(const float2*)(xb + 2 * i);
                    const float2 xi1 = *(const float2*)(xb + 2 * i + 2);
                    const float2 pt  = *(const float2*)(xb + 512);   // x[b,T,:]
                    const float tv = t[b0 + bl];
                    const float nv = (float)(dir ? i : (i + 1)) * (1.0f / 256.0f);
                    if (dir == 0) {  // [x_{i+1}, t, x_i, (i+1)/T, pt]
                        f0 = pkbf(xi1.x, xi1.y);
                        f1 = pkbf(tv, xi.x);
                        f2 = pkbf(xi.y, nv);
                    } else {         // [x_i, t, x_{i+1}, i/T, pt]
                        f0 = pkbf(xi.x, xi.y);
                        f1 = pkbf(tv, xi1.x);
                        f2 = pkbf(xi1.y, nv);
                    }
                    f3 = pkbf(pt.x, pt.y);
                }
                unsigned* fp = (unsigned*)&fbuf[p * 256 + lane * 8];
                fp[0] = f0; fp[1] = f1; fp[2] = f2; fp[3] = f3;
            }
            __syncthreads();  // feats ready (both pairs at same s)

            // ---- layer 1: h1[cols 64v..64v+64) for 32 rows ----
            #pragma unroll
            for (int mt = 0; mt < 2; ++mt) {
                short8 af = {0, 0, 0, 0, 0, 0, 0, 0};
                if (q == 0)
                    af = *(const short8*)&fbuf[p * 256 + (mt * 16 + c) * 8];
                floatx4 a0 = {b1v[0], b1v[0], b1v[0], b1v[0]};
                floatx4 a1 = {b1v[1], b1v[1], b1v[1], b1v[1]};
                floatx4 a2 = {b1v[2], b1v[2], b1v[2], b1v[2]};
                floatx4 a3 = {b1v[3], b1v[3], b1v[3], b1v[3]};
                a0 = MFMA16(af, w1f[0], a0);
                a1 = MFMA16(af, w1f[1], a1);
                a2 = MFMA16(af, w1f[2], a2);
                a3 = MFMA16(af, w1f[3], a3);
                const int rowb = mt * 16 + q * 4;
                #pragma unroll
                for (int rr = 0; rr < 4; ++rr) {
                    hp1[hphys(rowb + rr, (v << 5) + c)] =
                        pkbf(fmaxf(a0[rr], 0.0f), fmaxf(a1[rr], 0.0f));
                    hp1[hphys(rowb + rr, (v << 5) + 16 + c)] =
                        pkbf(fmaxf(a2[rr], 0.0f), fmaxf(a3[rr], 0.0f));
                }
            }
            __syncthreads();  // h1 complete

            // ---- layer 2: read full h1 (2x amp), write h2 ----
            // row = mt*16 + c -> row&15 == c: swizzle folds to base ^ (kt<<4).
            #pragma unroll
            for (int mt = 0; mt < 2; ++mt) {
                const unsigned* rp = &hp1[(mt * 16 + c) * 64];
                const int base = (q ^ c) << 2;
                short8 a0 = *(const short8*)&rp[base];
                short8 a1 = *(const short8*)&rp[base ^ 16];
                short8 a2 = *(const short8*)&rp[base ^ 32];
                short8 a3 = *(const short8*)&rp[base ^ 48];
                floatx4 s0 = {b2v[0], b2v[0], b2v[0], b2v[0]};
                floatx4 s1 = {b2v[1], b2v[1], b2v[1], b2v[1]};
                floatx4 s2 = {b2v[2], b2v[2], b2v[2], b2v[2]};
                floatx4 s3 = {b2v[3], b2v[3], b2v[3], b2v[3]};
                s0 = MFMA16(a0, w2f[0][0], s0); s1 = MFMA16(a0, w2f[1][0], s1);
                s2 = MFMA16(a0, w2f[2][0], s2); s3 = MFMA16(a0, w2f[3][0], s3);
                s0 = MFMA16(a1, w2f[0][1], s0); s1 = MFMA16(a1, w2f[1][1], s1);
                s2 = MFMA16(a1, w2f[2][1], s2); s3 = MFMA16(a1, w2f[3][1], s3);
                s0 = MFMA16(a2, w2f[0][2], s0); s1 = MFMA16(a2, w2f[1][2], s1);
                s2 = MFMA16(a2, w2f[2][2], s2); s3 = MFMA16(a2, w2f[3][2], s3);
                s0 = MFMA16(a3, w2f[0][3], s0); s1 = MFMA16(a3, w2f[1][3], s1);
                s2 = MFMA16(a3, w2f[2][3], s2); s3 = MFMA16(a3, w2f[3][3], s3);
                const int rowb = mt * 16 + q * 4;
                #pragma unroll
                for (int rr = 0; rr < 4; ++rr) {
                    hp2[hphys(rowb + rr, (v << 5) + c)] =
                        pkbf(fmaxf(s0[rr], 0.0f), fmaxf(s1[rr], 0.0f));
                    hp2[hphys(rowb + rr, (v << 5) + 16 + c)] =
                        pkbf(fmaxf(s2[rr], 0.0f), fmaxf(s3[rr], 0.0f));
                }
            }
            __syncthreads();  // h2 complete

            // ---- layer 3: wave v does row-block 16v, full k (4 MFMAs) ----
            {
                const unsigned short* w3p = w3img + ((q * 2 + (c & 1)) << 3);
                const int rowblk = v << 4;
                const unsigned* rp = &hp2[(rowblk + c) * 64];
                const int base = (q ^ c) << 2;
                short8 a0 = *(const short8*)&rp[base];
                short8 a1 = *(const short8*)&rp[base ^ 16];
                short8 a2 = *(const short8*)&rp[base ^ 32];
                short8 a3 = *(const short8*)&rp[base ^ 48];
                floatx4 ss = {b3c, b3c, b3c, b3c};
                ss = MFMA16(a0, *(const short8*)&w3p[0],   ss);
                ss = MFMA16(a1, *(const short8*)&w3p[64],  ss);
                ss = MFMA16(a2, *(const short8*)&w3p[128], ss);
                ss = MFMA16(a3, *(const short8*)&w3p[192], ss);
                if (c < 2) {
                    const int rb = r0 + rowblk + q * 4;
                    #pragma unroll
                    for (int rr = 0; rr < 4; ++rr) {
                        const int r = rb + rr;
                        if (r < 510) {
                            // idx = 512*bl + 2*pos + c, pos = (r-255bl)+1-dir
                            //     = 2r + 2*(r>=255) + 2(1-dir) + c  (no div)
                            const int idx = 2 * r + ((r >= 255) ? 2 : 0)
                                          + posoff + c;
                            atomicAdd(&accT[idx], ss[rr]);  // ds_add_f32
                        }
                    }
                }
            }
            // next tile's feats/h1/h2 writes ordered by its own barriers
        }
    }

    __syncthreads();  // accT complete (ds_add ordered by barrier)
    // ---- coalesced writeout: 1024 floats = out[b0..b0+1] ----
    ((float4*)(out + (size_t)b0 * 512))[tid] = ((const float4*)accT)[tid];
}

extern "C" void kernel_launch(void* const* d_in, const int* in_sizes, int n_in,
                              void* d_out, int out_size, void* d_ws, size_t ws_size,
                              hipStream_t stream) {
    (void)in_sizes; (void)n_in; (void)d_ws; (void)ws_size; (void)out_size;
    const float* x   = (const float*)d_in[0];
    const float* t   = (const float*)d_in[1];
    const float* fW1 = (const float*)d_in[2];
    const float* fb1 = (const float*)d_in[3];
    const float* fW2 = (const float*)d_in[4];
    const float* fb2 = (const float*)d_in[5];
    const float* fW3 = (const float*)d_in[6];
    const float* fb3 = (const float*)d_in[7];
    const float* gW1 = (const float*)d_in[8];
    const float* gb1 = (const float*)d_in[9];
    const float* gW2 = (const float*)d_in[10];
    const float* gb2 = (const float*)d_in[11];
    const float* gW3 = (const float*)d_in[12];
    const float* gb3 = (const float*)d_in[13];
    const float* iW1 = (const float*)d_in[14];
    const float* ib1 = (const float*)d_in[15];
    const float* iW2 = (const float*)d_in[16];
    const float* ib2 = (const float*)d_in[17];
    const float* iW3 = (const float*)d_in[18];
    const float* ib3 = (const float*)d_in[19];
    float* out = (float*)d_out;

    NeuralNet_37615323578557_kernel<<<dim3(2048), 256, 0, stream>>>(
        x, t, fW1, fb1, fW2, fb2, fW3, fb3,
        gW1, gb1, gW2, gb2, gW3, gb3,
        iW1, ib1, iW2, ib2, iW3, ib3, out);
}

// Round 6
// 262.399 us; speedup vs baseline: 4.5227x; 3.1294x over previous
//
#include <hip/hip_runtime.h>
#include <stdint.h>

typedef __attribute__((ext_vector_type(8))) short short8;
typedef __attribute__((ext_vector_type(4))) float floatx4;

#define MFMA16(a, b, c) __builtin_amdgcn_mfma_f32_16x16x32_bf16(a, b, c, 0, 0, 0)

// Pack two fp32 -> bf16 pair (lo, hi) in ONE v_perm_b32 after +0x8000
// round-half-up (vs software RNE: ~10 VALU -> 3 VALU per pair).
__device__ __forceinline__ unsigned pkbf(float lo, float hi) {
    const unsigned a = __builtin_bit_cast(unsigned, lo) + 0x8000u;
    const unsigned b = __builtin_bit_cast(unsigned, hi) + 0x8000u;
    return __builtin_amdgcn_perm(b, a, 0x07060302u);  // {b.hi16, a.hi16}
}
__device__ __forceinline__ unsigned short f2bf(float x) {
    unsigned u = __builtin_bit_cast(unsigned, x);
    u = (u + 0x7fffu + ((u >> 16) & 1u)) >> 16;  // RNE (cold paths only)
    return (unsigned short)u;
}

// Activation tiles are 64x128 bf16 viewed as u32 pairs: u32 index u of a row
// holds bf16 cols (2u, 2u+1). 16B chunks XOR-swizzled by row&15: b32 C-layout
// writes stay <=2-way (free), b128 A-frag reads are bank-balanced.
__device__ __forceinline__ int hphys(int row, int u) {
    return row * 64 + ((((u >> 2) ^ (row & 15)) << 2) | (u & 3));
}

// == R19 = R13 chassis (verified 196us) + feats DOUBLE-BUFFER ==
// R14-R18 post-mortem: the allocator splits the waves_per_eu budget into
// arch/acc halves; any structure whose ARCH live set (B-frags+addressing)
// exceeds ~84 spills (R18: w2f[4][4]=64 + rest > 84 -> 1.8GB scratch).
// R13's N-split (w2f=32, arch ~64) is the unique fit at the 128 budget.
// So: revert to R13 verbatim and remove the only barrier that doesn't
// protect a register-structure hazard: the per-tile feats barrier.
//  * fbuf -> 2 x 1KB buffers; feats for tile tt+1 staged INSIDE tile tt's
//    L2 phase (global loads hide under 32 MFMAs), ordered by the h2
//    barrier. In-loop barriers: 3 -> 2 per tile (24 -> 16 per dir).
//  * tile 0 feats staged in the weight-staging phase; one new prologue
//    barrier (w2f drain before h1 overwrites sbuf) replaces the old
//    tile-0 feats barrier.
//  * Everything else byte-identical to R13: 2048 WGs, 2 batches/WG,
//    N-split 32 cols/wave, W2 image via R6 rot-map, w3f LDS image,
//    sw==c folded A-frag swizzle, ds_add accT, (4,4).
__global__ __launch_bounds__(256)
__attribute__((amdgpu_waves_per_eu(4, 4)))
void NeuralNet_37615323578557_kernel(
        const float* __restrict__ x, const float* __restrict__ t,
        const float* __restrict__ fW1, const float* __restrict__ fb1,
        const float* __restrict__ fW2, const float* __restrict__ fb2,
        const float* __restrict__ fW3, const float* __restrict__ fb3,
        const float* __restrict__ gW1, const float* __restrict__ gb1,
        const float* __restrict__ gW2, const float* __restrict__ gb2,
        const float* __restrict__ gW3, const float* __restrict__ gb3,
        const float* __restrict__ iW1, const float* __restrict__ ib1,
        const float* __restrict__ iW2, const float* __restrict__ ib2,
        const float* __restrict__ iW3, const float* __restrict__ ib3,
        float* __restrict__ out) {
    __shared__ unsigned sbuf[8192];             // 32 KB: h1 | h2 (or W2 image)
    __shared__ unsigned short fbuf[2][64 * 8];  // 2 KB feats dbuf / init scratch
    __shared__ float accT[2 * 256 * 2];         // 4 KB output accumulator
    __shared__ unsigned short w3img[256];       // 512 B W3 B-frag image

    unsigned* const h1buf = sbuf;               // 16 KB (64 rows x 64 u32)
    unsigned* const h2buf = sbuf + 4096;        // 16 KB

    const int tid  = threadIdx.x;
    const int lane = tid & 63;
    const int w    = tid >> 6;      // wave 0..3
    const int c    = lane & 15;     // MFMA low index (m for A, n for B/C)
    const int q    = lane >> 4;     // MFMA quad
    const int b0   = blockIdx.x * 2;

    // ---- zero the output accumulator ----
    #pragma unroll
    for (int k = 0; k < 4; ++k) accT[tid + k * 256] = 0.0f;
    __syncthreads();

    // ---- init MLP: waves 0,1 handle b_local = w (pure fp32 VALU) ----
    // Scratch = fbuf[0] (1 KB); the dir-0 entry barrier orders completion
    // before the dir-0 feats[0] staging reuses it.
    if (w < 2) {
        float* h1s = (float*)&fbuf[0][0] + w * 128;
        const int b = b0 + w;
        const float* xb = x + (size_t)b * 514;
        const float f0 = xb[0], f1 = xb[1], f2 = t[b];
        const int u0 = lane, u1 = lane + 64;
        const float h0 = fmaxf(iW1[u0] * f0 + iW1[128 + u0] * f1 + iW1[256 + u0] * f2 + ib1[u0], 0.f);
        const float h1 = fmaxf(iW1[u1] * f0 + iW1[128 + u1] * f1 + iW1[256 + u1] * f2 + ib1[u1], 0.f);
        h1s[u0] = h0;
        h1s[u1] = h1;
        float a0 = ib2[lane], a1 = ib2[lane + 64];
        for (int k = 0; k < 128; ++k) {
            const float hv = h1s[k];
            a0 += hv * iW2[k * 128 + lane];
            a1 += hv * iW2[k * 128 + lane + 64];
        }
        a0 = fmaxf(a0, 0.f); a1 = fmaxf(a1, 0.f);
        float p0 = a0 * iW3[lane * 2 + 0] + a1 * iW3[(lane + 64) * 2 + 0];
        float p1 = a0 * iW3[lane * 2 + 1] + a1 * iW3[(lane + 64) * 2 + 1];
        #pragma unroll
        for (int m = 1; m < 64; m <<= 1) {
            p0 += __shfl_xor(p0, m, 64);
            p1 += __shfl_xor(p1, m, 64);
        }
        if (lane == 0) {
            accT[w * 512 + 0] += p0 + ib3[0];
            accT[w * 512 + 1] += p1 + ib3[1];
        }
    }

    const int wbase = w * 32;
    const int ucol  = w * 16 + c;   // u32 col index this lane writes

    for (int dir = 0; dir < 2; ++dir) {
        const float* W1 = dir ? gW1 : fW1;
        const float* B1 = dir ? gb1 : fb1;
        const float* W2 = dir ? gW2 : fW2;
        const float* B2 = dir ? gb2 : fb2;
        const float* W3 = dir ? gW3 : fW3;
        const float* B3 = dir ? gb3 : fb3;
        const int posoff = (1 - dir) * 2;

        // feats staging for 64 rows starting at r0f into dst (caller: tid<64)
        auto stage_feats = [&](int r0f, unsigned short* dst) {
            const int r = r0f + tid;
            unsigned v0 = 0, v1 = 0, v2 = 0, v3 = 0;
            if (r < 510) {
                const int bl = (r >= 255) ? 1 : 0;
                const int i  = r - bl * 255;
                const float* xb = x + (size_t)(b0 + bl) * 514;
                const float2 xi  = *(const float2*)(xb + 2 * i);
                const float2 xi1 = *(const float2*)(xb + 2 * i + 2);
                const float2 pt  = *(const float2*)(xb + 512);   // x[b,T,:]
                const float tv = t[b0 + bl];
                const float nv = (float)(dir ? i : (i + 1)) * (1.0f / 256.0f);
                if (dir == 0) {  // [x_{i+1}, t, x_i, (i+1)/T, pt]
                    v0 = pkbf(xi1.x, xi1.y);
                    v1 = pkbf(tv, xi.x);
                    v2 = pkbf(xi.y, nv);
                } else {         // [x_i, t, x_{i+1}, i/T, pt]
                    v0 = pkbf(xi.x, xi.y);
                    v1 = pkbf(tv, xi1.x);
                    v2 = pkbf(xi1.y, nv);
                }
                v3 = pkbf(pt.x, pt.y);
            }
            unsigned* fp = (unsigned*)&dst[tid * 8];
            fp[0] = v0; fp[1] = v1; fp[2] = v2; fp[3] = v3;
        };

        __syncthreads();  // prev dir's sbuf/fbuf/w3img reads / init done

        // ---- stage W2 B-frag image into sbuf (exactly 32 KB) ----
        // Element (k,n) -> block B=((n>>5)*2+(n&1))*4+(k>>5),
        //   ushort idx = B*512 + (((k>>3)&3)*16 + ((n>>1)&15))*8 + (k&7).
        // Thread t: rows {k0,k0+1} with k0=2(t&63), cols [c0,c0+32) with
        // float2-rotation -> write bank covers all 32 (R6: verified 0
        // conflicts). unroll 4 caps in-flight loads at 8 payload regs.
        {
            const int k0  = (tid & 63) << 1;
            const int c0  = (tid >> 6) << 5;
            const int rot = (tid >> 2) & 15;
            const int ks  = k0 >> 5;
            const int q2  = (k0 >> 3) & 3;
            const int j0  = k0 & 7;         // even
            const float* r0p = &W2[k0 * 128 + c0];
            const float* r1p = r0p + 128;
            const int usb = (q2 << 4) * 8 + j0;   // + B*512 + n2*8
            #pragma unroll 4
            for (int nn2 = 0; nn2 < 16; ++nn2) {
                const int off = ((nn2 + rot) & 15) << 1;
                const float2 v0 = *(const float2*)(r0p + off);
                const float2 v1 = *(const float2*)(r1p + off);
                #pragma unroll
                for (int e = 0; e < 2; ++e) {
                    const int n = c0 + off + e;
                    const unsigned pv = pkbf(e ? v0.y : v0.x, e ? v1.y : v1.x);
                    const int B = ((n >> 5) * 2 + (n & 1)) * 4 + ks;
                    const int us = B * 512 + ((n >> 1) & 15) * 8 + usb;
                    sbuf[us >> 1] = pv;
                }
            }
        }

        // ---- stage W3 B-frag image (512 B; k-pair per thread) ----
        // u32 idx = ks*32 + q2*8 + c2*4 + jp (= tid for tid<128); lane (q,c)
        // later reads ushort base (q*2 + (c&1))*8 + ks*64. (R8-verified.)
        if (tid < 128) {
            const int ks3 = tid >> 5, q3 = (tid >> 3) & 3;
            const int c3 = (tid >> 2) & 1, jp = tid & 3;
            const int k = ks3 * 32 + q3 * 8 + jp * 2;
            ((unsigned*)w3img)[tid] = pkbf(W3[k * 2 + c3], W3[(k + 1) * 2 + c3]);
        }

        // ---- prefetch tile-0 feats into fbuf[0] (dbuf prologue) ----
        if (tid < 64) stage_feats(0, &fbuf[0][0]);

        // ---- small weight frags (W1, biases) straight to regs ----
        short8 w1f[2];
        float  b1v[2], b2v[2];
        #pragma unroll
        for (int ntl = 0; ntl < 2; ++ntl) {
            const int col = wbase + 2 * c + ntl;
            b1v[ntl] = B1[col];
            b2v[ntl] = B2[col];
            short8 f = {0, 0, 0, 0, 0, 0, 0, 0};
            if (q == 0) {  // K padded 8 -> 32: only quad 0 holds real W1 rows
                #pragma unroll
                for (int j = 0; j < 8; ++j) f[j] = (short)f2bf(W1[j * 128 + col]);
            }
            w1f[ntl] = f;
        }
        const float b3c = (c < 2) ? B3[c] : 0.0f;
        __syncthreads();  // W2/W3 frag images + feats[0] complete

        // ---- w2f from LDS: 8 conflict-free ds_read_b128 per lane ----
        short8 w2f[2][4];
        {
            const unsigned short* img = (const unsigned short*)sbuf;
            #pragma unroll
            for (int ntl = 0; ntl < 2; ++ntl)
                #pragma unroll
                for (int ks = 0; ks < 4; ++ks)
                    w2f[ntl][ks] = *(const short8*)
                        &img[(((w * 2 + ntl) * 4 + ks) << 9) + lane * 8];
        }
        __syncthreads();  // w2f reads drained -> sbuf safe for h1/h2

        #pragma unroll 1
        for (int tt = 0; tt < 8; ++tt) {
            const unsigned short* fcur = &fbuf[tt & 1][0];

            // ---- layer 1: h1[cols wbase..wbase+32) for 64 rows ----
            #pragma unroll
            for (int mt = 0; mt < 4; ++mt) {
                short8 af = {0, 0, 0, 0, 0, 0, 0, 0};
                if (q == 0) af = *(const short8*)&fcur[(mt * 16 + c) * 8];
                floatx4 a0 = {b1v[0], b1v[0], b1v[0], b1v[0]};
                floatx4 a1 = {b1v[1], b1v[1], b1v[1], b1v[1]};
                a0 = MFMA16(af, w1f[0], a0);
                a1 = MFMA16(af, w1f[1], a1);
                const int rowb = mt * 16 + q * 4;
                #pragma unroll
                for (int rr = 0; rr < 4; ++rr)
                    h1buf[hphys(rowb + rr, ucol)] =
                        pkbf(fmaxf(a0[rr], 0.0f), fmaxf(a1[rr], 0.0f));
            }
            __syncthreads();  // h1 complete (also: prev tile's L3 done)

            // ---- prefetch NEXT tile's feats into the other buffer ----
            // Global loads issue here and retire under L2's 32 MFMAs; the
            // h2 barrier below orders the writes before tile tt+1's L1.
            if (tt < 7 && tid < 64)
                stage_feats((tt + 1) * 64, &fbuf[(tt + 1) & 1][0]);

            // ---- layer 2: read h1, write h2 (disjoint halves) ----
            // row = mt*16 + c -> row&15 == c, so the XOR swizzle folds to
            // base = (q^c)<<2 and (k+q)^c = base ^ (k<<2) for k in {4,8,12}.
            #pragma unroll
            for (int mt = 0; mt < 4; ++mt) {
                const unsigned* rp = &h1buf[(mt * 16 + c) * 64];
                const int base = (q ^ c) << 2;
                short8 a0 = *(const short8*)&rp[base];
                short8 a1 = *(const short8*)&rp[base ^ 16];
                short8 a2 = *(const short8*)&rp[base ^ 32];
                short8 a3 = *(const short8*)&rp[base ^ 48];
                floatx4 s0 = {b2v[0], b2v[0], b2v[0], b2v[0]};
                floatx4 s1 = {b2v[1], b2v[1], b2v[1], b2v[1]};
                s0 = MFMA16(a0, w2f[0][0], s0); s1 = MFMA16(a0, w2f[1][0], s1);
                s0 = MFMA16(a1, w2f[0][1], s0); s1 = MFMA16(a1, w2f[1][1], s1);
                s0 = MFMA16(a2, w2f[0][2], s0); s1 = MFMA16(a2, w2f[1][2], s1);
                s0 = MFMA16(a3, w2f[0][3], s0); s1 = MFMA16(a3, w2f[1][3], s1);
                const int rowb = mt * 16 + q * 4;
                #pragma unroll
                for (int rr = 0; rr < 4; ++rr)
                    h2buf[hphys(rowb + rr, ucol)] =
                        pkbf(fmaxf(s0[rr], 0.0f), fmaxf(s1[rr], 0.0f));
            }
            __syncthreads();  // h2 + feats[tt+1] complete

            // ---- layer 3: wave owns rows [16w,16w+16); ds_add into accT ----
            // W3 B-frags from the 512 B LDS image: 4 ds_read_b128, 8
            // distinct addrs + 8-way same-addr broadcast (conflict-free).
            // Lanes c>=2 read the (c&1) image: they pollute only C columns
            // c>=2, which are never read.
            {
                const int r0 = tt * 64;
                const unsigned* rp = &h2buf[(w * 16 + c) * 64];
                const int base = (q ^ c) << 2;
                short8 a0 = *(const short8*)&rp[base];
                short8 a1 = *(const short8*)&rp[base ^ 16];
                short8 a2 = *(const short8*)&rp[base ^ 32];
                short8 a3 = *(const short8*)&rp[base ^ 48];
                const unsigned short* w3p = w3img + ((q * 2 + (c & 1)) << 3);
                floatx4 s = {b3c, b3c, b3c, b3c};
                s = MFMA16(a0, *(const short8*)&w3p[0],   s);
                s = MFMA16(a1, *(const short8*)&w3p[64],  s);
                s = MFMA16(a2, *(const short8*)&w3p[128], s);
                s = MFMA16(a3, *(const short8*)&w3p[192], s);
                if (c < 2) {
                    const int rb = r0 + w * 16 + q * 4;
                    #pragma unroll
                    for (int rr = 0; rr < 4; ++rr) {
                        const int r = rb + rr;
                        if (r < 510) {
                            // idx = 512*bl + 2*pos + c, pos = (r-255bl)+1-dir
                            //     = 2r + 2*(r>=255) + 2(1-dir) + c  (no div)
                            const int idx = 2 * r + ((r >= 255) ? 2 : 0)
                                          + posoff + c;
                            atomicAdd(&accT[idx], s[rr]);  // ds_add_f32
                        }
                    }
                }
            }
            // next tile's h1 writes ordered by its own h1 barrier
        }
    }

    __syncthreads();  // accT complete (ds_add ordered by barrier)
    // ---- coalesced writeout: 1024 floats = out[b0..b0+1] ----
    ((float4*)(out + (size_t)b0 * 512))[tid] = ((const float4*)accT)[tid];
}

extern "C" void kernel_launch(void* const* d_in, const int* in_sizes, int n_in,
                              void* d_out, int out_size, void* d_ws, size_t ws_size,
                              hipStream_t stream) {
    (void)in_sizes; (void)n_in; (void)d_ws; (void)ws_size; (void)out_size;
    const float* x   = (const float*)d_in[0];
    const float* t   = (const float*)d_in[1];
    const float* fW1 = (const float*)d_in[2];
    const float* fb1 = (const float*)d_in[3];
    const float* fW2 = (const float*)d_in[4];
    const float* fb2 = (const float*)d_in[5];
    const float* fW3 = (const float*)d_in[6];
    const float* fb3 = (const float*)d_in[7];
    const float* gW1 = (const float*)d_in[8];
    const float* gb1 = (const float*)d_in[9];
    const float* gW2 = (const float*)d_in[10];
    const float* gb2 = (const float*)d_in[11];
    const float* gW3 = (const float*)d_in[12];
    const float* gb3 = (const float*)d_in[13];
    const float* iW1 = (const float*)d_in[14];
    const float* ib1 = (const float*)d_in[15];
    const float* iW2 = (const float*)d_in[16];
    const float* ib2 = (const float*)d_in[17];
    const float* iW3 = (const float*)d_in[18];
    const float* ib3 = (const float*)d_in[19];
    float* out = (float*)d_out;

    NeuralNet_37615323578557_kernel<<<dim3(2048), 256, 0, stream>>>(
        x, t, fW1, fb1, fW2, fb2, fW3, fb3,
        gW1, gb1, gW2, gb2, gW3, gb3,
        iW1, ib1, iW2, ib2, iW3, ib3, out);
}